// Round 1
// baseline (281.279 us; speedup 1.0000x reference)
//
#include <hip/hip_runtime.h>

#define HH 256
#define WW 256
#define CC 3
#define KK 9
#define OC 64

__global__ __launch_bounds__(256) void dcn_fused(
    const float* __restrict__ x,        // (B,3,256,256)
    const float* __restrict__ w_offset, // (18,3,3,3)
    const float* __restrict__ b_offset, // (18)
    const float* __restrict__ w_mask,   // (9,3,3,3)
    const float* __restrict__ b_mask,   // (9)
    const float* __restrict__ w_conv,   // (64,3,3,3)
    float* __restrict__ out)            // (B,64,256,256)
{
    const int j = threadIdx.x;          // column 0..255
    const int i = blockIdx.x & (HH - 1);
    const int b = blockIdx.x >> 8;

    const float* xb = x + (size_t)b * CC * HH * WW;

    // ---- load 3x3 neighborhood, 3 channels, zero-padded ----
    float xv[CC][3][3];
#pragma unroll
    for (int c = 0; c < CC; ++c) {
#pragma unroll
        for (int p = 0; p < 3; ++p) {
            int y = i + p - 1;
            bool yok = (unsigned)y < HH;
#pragma unroll
            for (int q = 0; q < 3; ++q) {
                int xx = j + q - 1;
                bool ok = yok && ((unsigned)xx < WW);
                xv[c][p][q] = ok ? xb[((size_t)c * HH + y) * WW + xx] : 0.0f;
            }
        }
    }

    // ---- per kernel-point: offset conv, mask conv, bilinear sample ----
    float s[KK][CC];  // sampled * mask
#pragma unroll
    for (int k = 0; k < KK; ++k) {
        float dy = b_offset[2 * k];
        float dx = b_offset[2 * k + 1];
        float mz = b_mask[k];
#pragma unroll
        for (int c = 0; c < CC; ++c) {
#pragma unroll
            for (int p = 0; p < 3; ++p) {
#pragma unroll
                for (int q = 0; q < 3; ++q) {
                    float v = xv[c][p][q];
                    dy = fmaf(w_offset[(((2 * k)     * CC + c) * 3 + p) * 3 + q], v, dy);
                    dx = fmaf(w_offset[(((2 * k + 1) * CC + c) * 3 + p) * 3 + q], v, dx);
                    mz = fmaf(w_mask[((k * CC + c) * 3 + p) * 3 + q], v, mz);
                }
            }
        }
        float m = 1.0f / (1.0f + __expf(-mz));

        float py = (float)i + (float)(k / 3 - 1) + dy;
        float px = (float)j + (float)(k % 3 - 1) + dx;
        float y0f = floorf(py), x0f = floorf(px);
        float wy = py - y0f, wx = px - x0f;
        int y0 = (int)y0f, x0 = (int)x0f;
        int y1 = y0 + 1, x1 = x0 + 1;

        float w00 = (1.0f - wy) * (1.0f - wx);
        float w01 = (1.0f - wy) * wx;
        float w10 = wy * (1.0f - wx);
        float w11 = wy * wx;

        bool v0y = (unsigned)y0 < HH, v1y = (unsigned)y1 < HH;
        bool v0x = (unsigned)x0 < WW, v1x = (unsigned)x1 < WW;
        int y0c = min(max(y0, 0), HH - 1), y1c = min(max(y1, 0), HH - 1);
        int x0c = min(max(x0, 0), WW - 1), x1c = min(max(x1, 0), WW - 1);

        float f00 = (v0y && v0x) ? w00 : 0.0f;
        float f01 = (v0y && v1x) ? w01 : 0.0f;
        float f10 = (v1y && v0x) ? w10 : 0.0f;
        float f11 = (v1y && v1x) ? w11 : 0.0f;

#pragma unroll
        for (int c = 0; c < CC; ++c) {
            const float* xc = xb + (size_t)c * HH * WW;
            float v00 = xc[y0c * WW + x0c];
            float v01 = xc[y0c * WW + x1c];
            float v10 = xc[y1c * WW + x0c];
            float v11 = xc[y1c * WW + x1c];
            s[k][c] = (v00 * f00 + v01 * f01 + v10 * f10 + v11 * f11) * m;
        }
    }

    // ---- epilogue: out[b,o,i,j] = sum_{c,k} s[k][c] * w_conv[o,c,k] ----
    float* ob = out + (size_t)b * OC * HH * WW + (size_t)i * WW + j;
#pragma unroll 4
    for (int o = 0; o < OC; ++o) {
        float acc = 0.0f;
#pragma unroll
        for (int c = 0; c < CC; ++c) {
#pragma unroll
            for (int k = 0; k < KK; ++k) {
                acc = fmaf(s[k][c], w_conv[(o * CC + c) * KK + k], acc);
            }
        }
        ob[(size_t)o * HH * WW] = acc;
    }
}

extern "C" void kernel_launch(void* const* d_in, const int* in_sizes, int n_in,
                              void* d_out, int out_size, void* d_ws, size_t ws_size,
                              hipStream_t stream) {
    const float* x        = (const float*)d_in[0];
    const float* w_offset = (const float*)d_in[1];
    const float* b_offset = (const float*)d_in[2];
    const float* w_mask   = (const float*)d_in[3];
    const float* b_mask   = (const float*)d_in[4];
    const float* w_conv   = (const float*)d_in[5];
    float* out = (float*)d_out;

    int B = in_sizes[0] / (CC * HH * WW);  // 16
    dim3 grid(B * HH);                     // one block per (b, row)
    dim3 block(WW);                        // one thread per column
    hipLaunchKernelGGL(dcn_fused, grid, block, 0, stream,
                       x, w_offset, b_offset, w_mask, b_mask, w_conv, out);
}

// Round 2
// 136.303 us; speedup vs baseline: 2.0636x; 2.0636x over previous
//
#include <hip/hip_runtime.h>

#define HH 256
#define WW 256
#define CC 3
#define KK 9
#define OC 64
#define KD 27    // C*K = flattened reduction dim
#define ROWS 40  // shorts per LDS row (80 B, 16B-aligned, padded vs 64B to spread banks)

typedef __attribute__((ext_vector_type(8))) short bf16x8;
typedef __attribute__((ext_vector_type(4))) float f32x4;

// round-to-nearest-even f32 -> bf16 (finite inputs)
static __device__ __forceinline__ short f2bf(float f) {
    unsigned u = __float_as_uint(f);
    unsigned r = (u + 0x7fffu + ((u >> 16) & 1u)) >> 16;
    return (short)r;
}

__global__ __launch_bounds__(256) void dcn_fused(
    const float* __restrict__ x,        // (B,3,256,256)
    const float* __restrict__ w_offset, // (18,3,3,3)
    const float* __restrict__ b_offset, // (18)
    const float* __restrict__ w_mask,   // (9,3,3,3)
    const float* __restrict__ b_mask,   // (9)
    const float* __restrict__ w_conv,   // (64,3,3,3) -> (64,27)
    float* __restrict__ out)            // (B,64,256,256)
{
    __shared__ __align__(16) short Slds[256 * ROWS];  // 20 KB, one row per pixel

    const int tid = threadIdx.x;        // pixel column j, also LDS row
    const int j = tid;
    const int i = blockIdx.x & (HH - 1);
    const int b = blockIdx.x >> 8;
    const int lane = tid & 63;
    const int wv = tid >> 6;

    const float* xb = x + (size_t)b * CC * HH * WW;

    // ---- load 3x3 neighborhood, 3 channels, zero-padded ----
    float xv[CC][3][3];
#pragma unroll
    for (int c = 0; c < CC; ++c) {
#pragma unroll
        for (int p = 0; p < 3; ++p) {
            int y = i + p - 1;
            bool yok = (unsigned)y < HH;
#pragma unroll
            for (int q = 0; q < 3; ++q) {
                int xx = j + q - 1;
                bool ok = yok && ((unsigned)xx < WW);
                xv[c][p][q] = ok ? xb[((size_t)c * HH + y) * WW + xx] : 0.0f;
            }
        }
    }

    // ---- per kernel-point: offset conv, mask conv, bilinear sample ----
    float s27[KD];  // sampled * mask, K-index = c*9 + k
#pragma unroll
    for (int k = 0; k < KK; ++k) {
        float dy = b_offset[2 * k];
        float dx = b_offset[2 * k + 1];
        float mz = b_mask[k];
#pragma unroll
        for (int c = 0; c < CC; ++c) {
#pragma unroll
            for (int p = 0; p < 3; ++p) {
#pragma unroll
                for (int q = 0; q < 3; ++q) {
                    float v = xv[c][p][q];
                    dy = fmaf(w_offset[(((2 * k)     * CC + c) * 3 + p) * 3 + q], v, dy);
                    dx = fmaf(w_offset[(((2 * k + 1) * CC + c) * 3 + p) * 3 + q], v, dx);
                    mz = fmaf(w_mask[((k * CC + c) * 3 + p) * 3 + q], v, mz);
                }
            }
        }
        float m = 1.0f / (1.0f + __expf(-mz));

        float py = (float)i + (float)(k / 3 - 1) + dy;
        float px = (float)j + (float)(k % 3 - 1) + dx;
        float y0f = floorf(py), x0f = floorf(px);
        float wy = py - y0f, wx = px - x0f;
        int y0 = (int)y0f, x0 = (int)x0f;
        int y1 = y0 + 1, x1 = x0 + 1;

        float w00 = (1.0f - wy) * (1.0f - wx);
        float w01 = (1.0f - wy) * wx;
        float w10 = wy * (1.0f - wx);
        float w11 = wy * wx;

        bool v0y = (unsigned)y0 < HH, v1y = (unsigned)y1 < HH;
        bool v0x = (unsigned)x0 < WW, v1x = (unsigned)x1 < WW;
        int y0c = min(max(y0, 0), HH - 1), y1c = min(max(y1, 0), HH - 1);
        int x0c = min(max(x0, 0), WW - 1), x1c = min(max(x1, 0), WW - 1);

        float f00 = (v0y && v0x) ? w00 : 0.0f;
        float f01 = (v0y && v1x) ? w01 : 0.0f;
        float f10 = (v1y && v0x) ? w10 : 0.0f;
        float f11 = (v1y && v1x) ? w11 : 0.0f;

#pragma unroll
        for (int c = 0; c < CC; ++c) {
            const float* xc = xb + (size_t)c * HH * WW;
            float v00 = xc[y0c * WW + x0c];
            float v01 = xc[y0c * WW + x1c];
            float v10 = xc[y1c * WW + x0c];
            float v11 = xc[y1c * WW + x1c];
            s27[c * KK + k] = (v00 * f00 + v01 * f01 + v10 * f10 + v11 * f11) * m;
        }
    }

    // ---- stage S row (bf16, padded to 32) into LDS ----
    short* rowp = &Slds[tid * ROWS];
#pragma unroll
    for (int ch = 0; ch < 4; ++ch) {
        bf16x8 v;
#pragma unroll
        for (int e = 0; e < 8; ++e) {
            int kd = ch * 8 + e;
            v[e] = (kd < KD) ? f2bf(s27[kd]) : (short)0;
        }
        *(bf16x8*)(rowp + ch * 8) = v;
    }

    __syncthreads();

    // ---- MFMA epilogue: out[64 oc x 64 px per wave] = W(64x27) * S(27x64) ----
    const int m = lane & 15;   // A row (oc within tile) / B col (pixel within group)
    const int kc = lane >> 4;  // k-chunk 0..3 (8 k each)

    bf16x8 afrag[4];
#pragma unroll
    for (int t = 0; t < 4; ++t) {
#pragma unroll
        for (int e = 0; e < 8; ++e) {
            int kd = kc * 8 + e;
            afrag[t][e] = (kd < KD) ? f2bf(w_conv[(t * 16 + m) * KD + kd]) : (short)0;
        }
    }

#pragma unroll
    for (int g = 0; g < 4; ++g) {
        int jj = wv * 64 + g * 16 + m;                         // pixel column
        const short* brp = &Slds[jj * ROWS + kc * 8];
        bf16x8 bfrag = *(const bf16x8*)brp;                    // ds_read_b128

        f32x4 acc[4];
#pragma unroll
        for (int t = 0; t < 4; ++t) {
            acc[t] = (f32x4){0.f, 0.f, 0.f, 0.f};
            acc[t] = __builtin_amdgcn_mfma_f32_16x16x32_bf16(afrag[t], bfrag, acc[t], 0, 0, 0);
        }

        float* op = out + (((size_t)b * OC) * HH + i) * WW + jj;
#pragma unroll
        for (int t = 0; t < 4; ++t) {
#pragma unroll
            for (int r = 0; r < 4; ++r) {
                op[(size_t)(t * 16 + kc * 4 + r) * (HH * WW)] = acc[t][r];
            }
        }
    }
}

extern "C" void kernel_launch(void* const* d_in, const int* in_sizes, int n_in,
                              void* d_out, int out_size, void* d_ws, size_t ws_size,
                              hipStream_t stream) {
    const float* x        = (const float*)d_in[0];
    const float* w_offset = (const float*)d_in[1];
    const float* b_offset = (const float*)d_in[2];
    const float* w_mask   = (const float*)d_in[3];
    const float* b_mask   = (const float*)d_in[4];
    const float* w_conv   = (const float*)d_in[5];
    float* out = (float*)d_out;

    int B = in_sizes[0] / (CC * HH * WW);  // 16
    dim3 grid(B * HH);                     // one block per (b, row)
    dim3 block(WW);                        // one thread per column
    hipLaunchKernelGGL(dcn_fused, grid, block, 0, stream,
                       x, w_offset, b_offset, w_mask, b_mask, w_conv, out);
}

// Round 3
// 132.827 us; speedup vs baseline: 2.1176x; 1.0262x over previous
//
#include <hip/hip_runtime.h>

#define HH 256
#define WW 256
#define CC 3
#define KK 9
#define OC 64
#define KD 27    // C*K flattened reduction dim
#define PST 72   // patch row stride, shorts (144 B, 16B-aligned, full-bank coverage)
#define DST 34   // D row stride, floats (136 B, 8B-aligned)
#define SST 40   // S row stride, shorts (80 B, 16B-aligned)
#define WRB 9216 // per-wave LDS region bytes

typedef __attribute__((ext_vector_type(8))) short bf16x8;
typedef __attribute__((ext_vector_type(4))) float f32x4;
typedef __attribute__((ext_vector_type(2))) float f32x2;

// round-to-nearest-even f32 -> bf16
static __device__ __forceinline__ short f2bf(float f) {
    unsigned u = __float_as_uint(f);
    return (short)((u + 0x7fffu + ((u >> 16) & 1u)) >> 16);
}

__global__ __launch_bounds__(256) void dcn_fused(
    const float* __restrict__ x,        // (B,3,256,256)
    const float* __restrict__ w_offset, // (18,27) flattened
    const float* __restrict__ b_offset, // (18)
    const float* __restrict__ w_mask,   // (9,27)
    const float* __restrict__ b_mask,   // (9)
    const float* __restrict__ w_conv,   // (64,27)
    float* __restrict__ out)            // (B,64,256,256)
{
    __shared__ __align__(16) char LDSBUF[4 * WRB];

    const int tid = threadIdx.x;        // pixel column j
    const int j = tid;
    const int i = blockIdx.x & (HH - 1);
    const int b = blockIdx.x >> 8;
    const int lane = tid & 63;
    const int wv = tid >> 6;
    const int fm = lane & 15;           // fragment row/col index
    const int kc = lane >> 4;           // k-chunk 0..3

    char* wbase = LDSBUF + wv * WRB;
    short* patch = (short*)wbase;
    float* Df = (float*)wbase;
    short* S = (short*)wbase;

    const float* xb = x + (size_t)b * CC * HH * WW;

    // ---- load 3x3 neighborhood (zero-padded), kd = c*9 + p*3 + q ----
    float xv[32];
#pragma unroll
    for (int c = 0; c < CC; ++c) {
#pragma unroll
        for (int p = 0; p < 3; ++p) {
            int y = i + p - 1;
            bool yok = (unsigned)y < HH;
#pragma unroll
            for (int q = 0; q < 3; ++q) {
                int xx = j + q - 1;
                bool ok = yok && ((unsigned)xx < WW);
                xv[c * 9 + p * 3 + q] = ok ? xb[((size_t)c * HH + y) * WW + xx] : 0.0f;
            }
        }
    }
#pragma unroll
    for (int kd = KD; kd < 32; ++kd) xv[kd] = 0.0f;

    // ---- stage patch hi/lo bf16 into per-wave LDS (row = lane) ----
    {
        short hs[32], ls[32];
#pragma unroll
        for (int kd = 0; kd < 32; ++kd) {
            unsigned u = __float_as_uint(xv[kd]);
            hs[kd] = (short)(u >> 16);
            float d = xv[kd] - __uint_as_float(u & 0xffff0000u);
            ls[kd] = (short)(__float_as_uint(d) >> 16);
        }
        short* rp = patch + lane * PST;
#pragma unroll
        for (int o = 0; o < 4; ++o) {
            bf16x8 vh, vl;
#pragma unroll
            for (int e = 0; e < 8; ++e) { vh[e] = hs[o * 8 + e]; vl[e] = ls[o * 8 + e]; }
            *(bf16x8*)(rp + o * 8) = vh;
            *(bf16x8*)(rp + 32 + o * 8) = vl;
        }
    }

    // ---- build conv W fragments (hi/lo) + bias C-init ----
    bf16x8 whi[2], wlo[2];
#pragma unroll
    for (int t = 0; t < 2; ++t) {
        int ch = t * 16 + fm;           // 0..31; 0..17 offset, 18..26 mask, 27..31 zero
        int cho = min(ch, 17);
        int chm = min(max(ch - 18, 0), 8);
#pragma unroll
        for (int e = 0; e < 8; ++e) {
            int kd = kc * 8 + e;
            int kdc = (kd < KD) ? kd : 0;
            float wo = w_offset[cho * KD + kdc];
            float wm = w_mask[chm * KD + kdc];
            float val = (kd < KD) ? (ch < 18 ? wo : (ch < KD ? wm : 0.0f)) : 0.0f;
            unsigned u = __float_as_uint(val);
            whi[t][e] = (short)(u >> 16);
            float d = val - __uint_as_float(u & 0xffff0000u);
            wlo[t][e] = (short)(__float_as_uint(d) >> 16);
        }
    }
    f32x4 cbias[2];
#pragma unroll
    for (int t = 0; t < 2; ++t) {
#pragma unroll
        for (int r = 0; r < 4; ++r) {
            int ch = t * 16 + kc * 4 + r;
            float bo = b_offset[min(ch, 17)];
            float bm = b_mask[min(max(ch - 18, 0), 8)];
            cbias[t][r] = ch < 18 ? bo : (ch < KD ? bm : 0.0f);
        }
    }

    // ---- conv MFMA: D[32ch][64px] = W*P + bias (read ALL patch before writing D) ----
    f32x4 dacc[4][2];
#pragma unroll
    for (int g = 0; g < 4; ++g) {
        const short* pr = patch + (g * 16 + fm) * PST + kc * 8;
        bf16x8 phi = *(const bf16x8*)pr;
        bf16x8 plo = *(const bf16x8*)(pr + 32);
#pragma unroll
        for (int t = 0; t < 2; ++t) {
            f32x4 a = __builtin_amdgcn_mfma_f32_16x16x32_bf16(whi[t], phi, cbias[t], 0, 0, 0);
            a = __builtin_amdgcn_mfma_f32_16x16x32_bf16(whi[t], plo, a, 0, 0, 0);
            a = __builtin_amdgcn_mfma_f32_16x16x32_bf16(wlo[t], phi, a, 0, 0, 0);
            dacc[g][t] = a;
        }
    }
#pragma unroll
    for (int g = 0; g < 4; ++g) {
#pragma unroll
        for (int t = 0; t < 2; ++t) {
            float* dp = Df + (g * 16 + fm) * DST + (t * 16 + kc * 4);
            *(f32x2*)dp = (f32x2){dacc[g][t][0], dacc[g][t][1]};
            *(f32x2*)(dp + 2) = (f32x2){dacc[g][t][2], dacc[g][t][3]};
        }
    }

    // ---- sampling: coords from LDS D (row = lane), gathers from global x ----
    const float* Drow = Df + lane * DST;
    float s27[KD];
#pragma unroll
    for (int k = 0; k < KK; ++k) {
        f32x2 dydx = *(const f32x2*)(Drow + 2 * k);
        float dy = dydx[0], dx = dydx[1];
        float mzv = Drow[18 + k];
        float msk = 1.0f / (1.0f + __expf(-mzv));

        float py = (float)i + (float)(k / 3 - 1) + dy;
        float px = (float)j + (float)(k % 3 - 1) + dx;
        float y0f = floorf(py), x0f = floorf(px);
        float wy = py - y0f, wx = px - x0f;
        int y0 = (int)y0f, x0 = (int)x0f;
        int y1 = y0 + 1, x1 = x0 + 1;

        float w00 = (1.0f - wy) * (1.0f - wx);
        float w01 = (1.0f - wy) * wx;
        float w10 = wy * (1.0f - wx);
        float w11 = wy * wx;

        bool v0y = (unsigned)y0 < HH, v1y = (unsigned)y1 < HH;
        bool v0x = (unsigned)x0 < WW, v1x = (unsigned)x1 < WW;
        int y0c = min(max(y0, 0), HH - 1), y1c = min(max(y1, 0), HH - 1);
        int x0c = min(max(x0, 0), WW - 1), x1c = min(max(x1, 0), WW - 1);

        float f00 = (v0y && v0x) ? w00 : 0.0f;
        float f01 = (v0y && v1x) ? w01 : 0.0f;
        float f10 = (v1y && v0x) ? w10 : 0.0f;
        float f11 = (v1y && v1x) ? w11 : 0.0f;

#pragma unroll
        for (int c = 0; c < CC; ++c) {
            const float* xc = xb + (size_t)c * HH * WW;
            float v00 = xc[y0c * WW + x0c];
            float v01 = xc[y0c * WW + x1c];
            float v10 = xc[y1c * WW + x0c];
            float v11 = xc[y1c * WW + x1c];
            s27[c * KK + k] = (v00 * f00 + v01 * f01 + v10 * f10 + v11 * f11) * msk;
        }
    }

    // ---- stage S row (bf16, zero-padded to 32) ----
    {
        short* rowp = S + lane * SST;
#pragma unroll
        for (int o = 0; o < 4; ++o) {
            bf16x8 v;
#pragma unroll
            for (int e = 0; e < 8; ++e) {
                int kd = o * 8 + e;
                v[e] = (kd < KD) ? f2bf(s27[kd]) : (short)0;
            }
            *(bf16x8*)(rowp + o * 8) = v;
        }
    }

    // ---- MFMA epilogue: out[64oc x 64px per wave] ----
    bf16x8 afrag[4];
#pragma unroll
    for (int t = 0; t < 4; ++t) {
#pragma unroll
        for (int e = 0; e < 8; ++e) {
            int kd = kc * 8 + e;
            afrag[t][e] = (kd < KD) ? f2bf(w_conv[(t * 16 + fm) * KD + kd]) : (short)0;
        }
    }

#pragma unroll
    for (int g = 0; g < 4; ++g) {
        int jj = wv * 64 + g * 16 + fm;
        bf16x8 bfrag = *(const bf16x8*)(S + (g * 16 + fm) * SST + kc * 8);

        f32x4 acc[4];
#pragma unroll
        for (int t = 0; t < 4; ++t) {
            acc[t] = (f32x4){0.f, 0.f, 0.f, 0.f};
            acc[t] = __builtin_amdgcn_mfma_f32_16x16x32_bf16(afrag[t], bfrag, acc[t], 0, 0, 0);
        }

        float* op = out + (((size_t)b * OC) * HH + i) * WW + jj;
#pragma unroll
        for (int t = 0; t < 4; ++t) {
#pragma unroll
            for (int r = 0; r < 4; ++r) {
                op[(size_t)(t * 16 + kc * 4 + r) * (HH * WW)] = acc[t][r];
            }
        }
    }
}

extern "C" void kernel_launch(void* const* d_in, const int* in_sizes, int n_in,
                              void* d_out, int out_size, void* d_ws, size_t ws_size,
                              hipStream_t stream) {
    const float* x        = (const float*)d_in[0];
    const float* w_offset = (const float*)d_in[1];
    const float* b_offset = (const float*)d_in[2];
    const float* w_mask   = (const float*)d_in[3];
    const float* b_mask   = (const float*)d_in[4];
    const float* w_conv   = (const float*)d_in[5];
    float* out = (float*)d_out;

    int B = in_sizes[0] / (CC * HH * WW);  // 16
    dim3 grid(B * HH);                     // one block per (b, row)
    dim3 block(WW);                        // one thread per column
    hipLaunchKernelGGL(dcn_fused, grid, block, 0, stream,
                       x, w_offset, b_offset, w_mask, b_mask, w_conv, out);
}